// Round 21
// baseline (77.851 us; speedup 1.0000x reference)
//
#include <hip/hip_runtime.h>
#include <math.h>

#define B_    2
#define T_    2048
#define EMB_  128
#define NH_   8
#define M_    9
#define P_    36
#define GADD_ 2

typedef _Float16 f16;
typedef __attribute__((ext_vector_type(2))) _Float16 f16x2;
typedef __attribute__((ext_vector_type(4))) _Float16 f16x4;
typedef __attribute__((ext_vector_type(8))) _Float16 f16x8;
typedef __attribute__((ext_vector_type(4))) float f32x4;

// ---------------- Threefry-2x32 (jax PRNG) ----------------
__device__ __forceinline__ unsigned rotl32(unsigned x, int r){ return (x<<r)|(x>>(32-r)); }

struct U2 { unsigned x, y; };

__device__ __forceinline__ U2 tf2x32(U2 key, U2 ctr){
  unsigned ks[3] = { key.x, key.y, key.x ^ key.y ^ 0x1BD11BDAu };
  unsigned x0 = ctr.x + ks[0], x1 = ctr.y + ks[1];
  const int rotA[4] = {13,15,26,6}, rotB[4] = {17,29,16,24};
  #pragma unroll
  for (int r = 0; r < 5; ++r){
    const int* rr = (r & 1) ? rotB : rotA;
    #pragma unroll
    for (int i = 0; i < 4; ++i){ x0 += x1; x1 = rotl32(x1, rr[i]); x1 ^= x0; }
    x0 += ks[(r+1)%3];
    x1 += ks[(r+2)%3] + (unsigned)(r+1);
  }
  return { x0, x1 };
}

// randint(key(42),(B,T,M,GADD),0,T), partitionable threefry path.
__device__ unsigned glob_rand(unsigned f){
  U2 k2 = tf2x32({0u, 42u}, {0u, 1u});
  U2 o  = tf2x32(k2, {0u, f});
  return (o.x ^ o.y) & (unsigned)(T_-1);
}

__device__ __forceinline__ f16x2 as_f16x2(unsigned u){ return __builtin_bit_cast(f16x2, u); }
__device__ __forceinline__ unsigned as_u32(f16x2 v){ return __builtin_bit_cast(unsigned, v); }

// ---------------- kernel 0: fused prep (tconvQKV | tconvWu | idx+weights) ----------------
__device__ __forceinline__ void tconv_body(const float* __restrict__ A,
    f16* __restrict__ o, int R, int C, int r0, int c0, float scale,
    float (*tile)[33]){
  const int tx = threadIdx.x & 31, ty = threadIdx.x >> 5;
  #pragma unroll
  for (int i = 0; i < 32; i += 8)
    tile[ty+i][tx] = A[(size_t)(r0+ty+i)*C + c0+tx];
  __syncthreads();
  #pragma unroll
  for (int i = 0; i < 32; i += 8)
    o[(size_t)(c0+ty+i)*R + (r0+tx)] = (f16)(tile[tx][ty+i] * scale);
}

__global__ __launch_bounds__(256) void prep_kernel(
    const float* __restrict__ Wq, const float* __restrict__ Wk, const float* __restrict__ Wv,
    f16* __restrict__ WT,
    const float* __restrict__ Wu, f16* __restrict__ WuT,
    const float* __restrict__ sp, const float* __restrict__ mvals,
    int* __restrict__ idx_out, float* __restrict__ w_out){
  __shared__ float tile[32][33];
  __shared__ int   s_idx[4][P_];
  __shared__ float s_dens[4][P_][M_];
  __shared__ float s_col[4][M_];
  const int bid = blockIdx.x;
  const float sc = 0.29730177875068026f; // 128^-0.25

  if (bid < 384){
    const int z = bid >> 7, rem = bid & 127;
    const int by = rem >> 5, bx = rem & 31;       // [128][1024]: 4 x 32 tiles
    const float* A = (z==0) ? Wq : (z==1) ? Wk : Wv;
    tconv_body(A, WT + (size_t)z*1024*128, 128, 1024, by*32, bx*32, (z<2)?sc:1.0f, tile);
    return;
  }
  if (bid < 512){
    const int idx2 = bid - 384;
    const int by = idx2 >> 2, bx = idx2 & 3;      // [1024][128]: 32 x 4 tiles
    tconv_body(Wu, WuT, 1024, 128, by*32, bx*32, 1.0f, tile);
    return;
  }

  // ---- idx + weights: 4 bt per block (one per wave) ----
  const int g  = threadIdx.x >> 6;
  const int p  = threadIdx.x & 63;
  const int bt = (bid - 512)*4 + g;
  const int t  = bt & (T_-1);

  const float dil  = sp[0];
  const float xs   = sp[1] + 2.0f;
  const float sigma = xs + log1pf(expf(-xs)) + 1e-7f;

  if (p < P_){
    const int m = p >> 2, j = p & 3;
    const float mean = fminf(fmaxf((float)t + (float)(m-4)*dil, 0.f), (float)(T_-1));
    int id;
    if      (j == 0) id = (int)floorf(mean);
    else if (j == 1) id = min((int)floorf(mean) + 1, T_-1);
    else {
      const unsigned f = ((unsigned)bt * M_ + (unsigned)m) * GADD_ + (unsigned)(j-2);
      id = (int)glob_rand(f);
    }
    s_idx[g][p] = id;
  }
  __syncthreads();
  if (p < P_){
    const int myid = s_idx[g][p];
    bool dup = false;
    for (int q = 0; q < p; ++q) dup |= (s_idx[g][q] == myid);
    const float pf = (float)myid;
    #pragma unroll
    for (int m = 0; m < M_; ++m){
      const float mean = fminf(fmaxf((float)t + (float)(m-4)*dil, 0.f), (float)(T_-1));
      const float d = (pf - mean) / sigma;
      s_dens[g][p][m] = dup ? 0.f : expf(-0.5f * d * d);
    }
  }
  __syncthreads();
  if (p < M_){
    float s = 0.f;
    for (int q = 0; q < P_; ++q) s += s_dens[g][q][p];
    s_col[g][p] = s;
  }
  __syncthreads();
  if (p < P_){
    float w = 0.f;
    #pragma unroll
    for (int m = 0; m < M_; ++m) w += s_dens[g][p][m] / s_col[g][m] * mvals[m];
    idx_out[bt*P_ + p] = s_idx[g][p];
    w_out[bt*P_ + p]   = w;
  }
}

// ---------------- kernel 2: QKV via f16 MFMA, inline x-conversion ----------------
// grid (16, 64), 256 thr = 4 waves; wave: 16M x 64N, K=128, 3 outputs.
// A-fragments read directly from f32 x (2 MB, L2-resident) and converted in-reg.
__global__ __launch_bounds__(256) void qkv_mfma_kernel(const float* __restrict__ x,
    const f16* __restrict__ WT,
    f16* __restrict__ Qh, f16* __restrict__ Kh, f16* __restrict__ Vh){
  const int w  = threadIdx.x >> 6, l = threadIdx.x & 63;
  const int m0 = blockIdx.y*64 + w*16;
  const int n0 = blockIdx.x*64;
  const int lr = l & 15, lk = l >> 4;

  __shared__ f16 s_t[4][16][72];   // per-wave transpose tile, 9.2 KB

  f16x8 a[4];
  #pragma unroll
  for (int kc = 0; kc < 4; ++kc){
    const float* xp = x + (size_t)(m0+lr)*128 + kc*32 + lk*8;
    float4 v0 = *(const float4*)(xp);
    float4 v1 = *(const float4*)(xp + 4);
    f16x8 av = { (f16)v0.x, (f16)v0.y, (f16)v0.z, (f16)v0.w,
                 (f16)v1.x, (f16)v1.y, (f16)v1.z, (f16)v1.w };
    a[kc] = av;
  }

  for (int z = 0; z < 3; ++z){
    const f16* __restrict__ WTz = WT + (size_t)z * 1024 * 128;
    f16* __restrict__ Outh = (z==0) ? Qh : (z==1) ? Kh : Vh;
    f32x4 acc[4] = {};
    #pragma unroll
    for (int nf = 0; nf < 4; ++nf){
      #pragma unroll
      for (int kc = 0; kc < 4; ++kc){
        f16x8 b = *(const f16x8*)(WTz + (size_t)(n0+nf*16+lr)*128 + kc*32 + lk*8);
        acc[nf] = __builtin_amdgcn_mfma_f32_16x16x32_f16(a[kc], b, acc[nf], 0, 0, 0);
      }
    }
    // fragment -> wave-local LDS tile (no barrier: single-wave producer/consumer)
    #pragma unroll
    for (int nf = 0; nf < 4; ++nf){
      #pragma unroll
      for (int r = 0; r < 4; ++r)
        s_t[w][lk*4 + r][nf*16 + lr] = (f16)acc[nf][r];
    }
    // coalesced store: 2 x (8 rows x 128B lines)
    #pragma unroll
    for (int half = 0; half < 2; ++half){
      const int row = (l >> 3) + half*8;
      const int seg = l & 7;
      f16x8 v = *(const f16x8*)(&s_t[w][row][seg*8]);
      *(f16x8*)(Outh + (size_t)(m0+row)*1024 + n0 + seg*8) = v;
    }
  }
}

// ---------------- kernel 3: gather-attention (barrier-free, shfl broadcasts) ----------------
// grid (4096, 2), 256 thr = 4 waves = 4 heads (h = by*4 + w).
// Lane: pg=lane>>4 owns points 4c+pg (c=0..8); li=lane&15 owns dims li*8..+8.
#define RSTR 37
#define NHB  4
__global__ __launch_bounds__(256) void attn_kernel(const f16* __restrict__ Qh,
    const f16* __restrict__ K, const f16* __restrict__ V,
    const int* __restrict__ idx, const float* __restrict__ wts,
    f16* __restrict__ outh){
  const int bid = blockIdx.x;
  const int bt  = ((bid & 7) << 9) | (bid >> 3);   // XCD swizzle, bijective
  const int b   = bt >> 11;
  const int hw   = threadIdx.x >> 6, lane = threadIdx.x & 63;
  const int h    = blockIdx.y*NHB + hw;
  const int pg = lane >> 4, li = lane & 15;
  const int pcol = (lane < P_) ? lane : 0;

  __shared__ float s_red[NHB][16*RSTR];   // wave-local only, 9.5 KB

  // per-lane broadcast loads (144B region -> 3 cache lines, coalescer merges)
  int ko[9];
  #pragma unroll
  for (int c = 0; c < 9; ++c) ko[c] = idx[bt*P_ + 4*c + pg] << 10;
  const float wv = wts[bt*P_ + pcol];

  const size_t rowBase = (size_t)bt*1024 + h*EMB_;
  const uint4 qu = *(const uint4*)(Qh + rowBase + li*8);
  const f16x2 q01 = as_f16x2(qu.x), q23 = as_f16x2(qu.y);
  const f16x2 q45 = as_f16x2(qu.z), q67 = as_f16x2(qu.w);
  const f16* __restrict__ Kb = K + (size_t)b*T_*1024 + h*EMB_ + li*8;
  const f16* __restrict__ Vb = V + (size_t)b*T_*1024 + h*EMB_ + li*8;

  // ---- Phase A: 9 uint4 K loads; 8-dim partial dots ----
  uint4 kU[9];
  #pragma unroll
  for (int c = 0; c < 9; ++c) kU[c] = *(const uint4*)(Kb + ko[c]);

  float pr[9];
  #pragma unroll
  for (int c = 0; c < 9; ++c){
    pr[c] = __builtin_amdgcn_fdot2(as_f16x2(kU[c].x), q01,
            __builtin_amdgcn_fdot2(as_f16x2(kU[c].y), q23,
            __builtin_amdgcn_fdot2(as_f16x2(kU[c].z), q45,
            __builtin_amdgcn_fdot2(as_f16x2(kU[c].w), q67, 0.f, false),
            false), false), false);
  }

  // ---- Phase B: LDS transpose (wave-local), column sum over 16 li-rows ----
  float* __restrict__ red = s_red[hw];
  {
    float* __restrict__ dst = red + li*RSTR + pg;
    #pragma unroll
    for (int c = 0; c < 9; ++c) dst[4*c] = pr[c];
  }
  float s0=0.f, s1=0.f, s2=0.f, s3=0.f;
  #pragma unroll
  for (int r = 0; r < 16; r += 4){
    s0 += red[(r+0)*RSTR + pcol];
    s1 += red[(r+1)*RSTR + pcol];
    s2 += red[(r+2)*RSTR + pcol];
    s3 += red[(r+3)*RSTR + pcol];
  }
  const float logit = (s0+s1)+(s2+s3);

  // ---- softmax (lane-per-point) ----
  float val = (lane < P_) ? logit * wv : -INFINITY;
  float mx = val;
  #pragma unroll
  for (int off = 32; off; off >>= 1) mx = fmaxf(mx, __shfl_xor(mx, off));
  float e = (lane < P_) ? expf(val - mx) : 0.f;
  float s = e;
  #pragma unroll
  for (int off = 32; off; off >>= 1) s += __shfl_xor(s, off);
  const float aval = e / s;

  // ---- Phase C: 9 uint4 V loads, packed f16 fma; weights via shfl broadcast ----
  f16x2 a01 = {(f16)0.f,(f16)0.f}, a23 = a01, a45 = a01, a67 = a01;
  #pragma unroll
  for (int c = 0; c < 9; ++c){
    const f16 awh = (f16)__shfl(aval, 4*c + pg);
    const f16x2 vw = { awh, awh };
    const uint4 u = *(const uint4*)(Vb + ko[c]);
    a01 = vw * as_f16x2(u.x) + a01;
    a23 = vw * as_f16x2(u.y) + a23;
    a45 = vw * as_f16x2(u.z) + a45;
    a67 = vw * as_f16x2(u.w) + a67;
  }
  // fold over the 4 pg groups
  a01 = a01 + as_f16x2(__shfl_xor((int)as_u32(a01), 16));
  a23 = a23 + as_f16x2(__shfl_xor((int)as_u32(a23), 16));
  a45 = a45 + as_f16x2(__shfl_xor((int)as_u32(a45), 16));
  a67 = a67 + as_f16x2(__shfl_xor((int)as_u32(a67), 16));
  a01 = a01 + as_f16x2(__shfl_xor((int)as_u32(a01), 32));
  a23 = a23 + as_f16x2(__shfl_xor((int)as_u32(a23), 32));
  a45 = a45 + as_f16x2(__shfl_xor((int)as_u32(a45), 32));
  a67 = a67 + as_f16x2(__shfl_xor((int)as_u32(a67), 32));
  if (pg == 0){
    uint4 pck = { as_u32(a01), as_u32(a23), as_u32(a45), as_u32(a67) };
    *(uint4*)(outh + rowBase + li*8) = pck;
  }
}

// ---------------- kernel 4: fused output GEMM (in-block split-K) + bias ----------------
// grid (256 m-tiles, 2 n-halves), 256 thr = 4 waves. Block: 16 rows x 64 cols.
__global__ __launch_bounds__(256) void out_fused_mfma(const f16* __restrict__ Ah,
    const f16* __restrict__ WuT, const float* __restrict__ bu,
    float* __restrict__ out){
  const int w  = threadIdx.x >> 6, l = threadIdx.x & 63;
  const int m0 = blockIdx.x*16;
  const int n0 = blockIdx.y*64;
  const int k0 = w*256;
  const int lr = l & 15, lk = l >> 4;

  __shared__ float s_part[4][16][64];   // 16 KB

  const f16* __restrict__ arow = Ah + (size_t)(m0+lr)*1024 + k0 + lk*8;
  f32x4 acc[4] = {};
  #pragma unroll
  for (int kc = 0; kc < 8; ++kc){
    f16x8 a = *(const f16x8*)(arow + kc*32);
    #pragma unroll
    for (int nf = 0; nf < 4; ++nf){
      f16x8 b = *(const f16x8*)(WuT + (size_t)(n0+nf*16+lr)*1024 + k0 + kc*32 + lk*8);
      acc[nf] = __builtin_amdgcn_mfma_f32_16x16x32_f16(a, b, acc[nf], 0, 0, 0);
    }
  }
  #pragma unroll
  for (int nf = 0; nf < 4; ++nf){
    #pragma unroll
    for (int r = 0; r < 4; ++r)
      s_part[w][lk*4 + r][nf*16 + lr] = acc[nf][r];
  }
  __syncthreads();

  // reduce: 1024 outputs = 256 thr x float4
  const int r  = threadIdx.x >> 4;          // 0..15
  const int c0 = (threadIdx.x & 15) * 4;    // 0..60
  float4 a0 = *(const float4*)(&s_part[0][r][c0]);
  float4 a1 = *(const float4*)(&s_part[1][r][c0]);
  float4 a2 = *(const float4*)(&s_part[2][r][c0]);
  float4 a3 = *(const float4*)(&s_part[3][r][c0]);
  float4 bias = *(const float4*)(bu + n0 + c0);
  float4 v = { (a0.x+a1.x)+(a2.x+a3.x)+bias.x,
               (a0.y+a1.y)+(a2.y+a3.y)+bias.y,
               (a0.z+a1.z)+(a2.z+a3.z)+bias.z,
               (a0.w+a1.w)+(a2.w+a3.w)+bias.w };
  *(float4*)(out + (size_t)(m0+r)*128 + n0 + c0) = v;
}

// ---------------- launch ----------------
extern "C" void kernel_launch(void* const* d_in, const int* in_sizes, int n_in,
                              void* d_out, int out_size, void* d_ws, size_t ws_size,
                              hipStream_t stream){
  (void)in_sizes; (void)n_in; (void)out_size; (void)ws_size;
  const float* x    = (const float*)d_in[0];
  const float* sp   = (const float*)d_in[1];
  const float* mvl  = (const float*)d_in[2];
  const float* Wq   = (const float*)d_in[3];
  const float* Wk   = (const float*)d_in[4];
  const float* Wv   = (const float*)d_in[5];
  const float* Wu   = (const float*)d_in[6];
  const float* bu   = (const float*)d_in[7];
  float* out = (float*)d_out;

  const size_t n = (size_t)B_*NH_*T_*EMB_;       // 4,194,304
  f16*   Qh    = (f16*)d_ws;                     // n
  f16*   Kh    = Qh + n;                         // n
  f16*   Vh    = Kh + n;                         // n
  f16*   attnh = Vh + n;                         // n
  f16*   WT    = attnh + n;                      // 3*131072
  f16*   WuT   = WT + 3*131072;                  // 131072
  int*   idxb  = (int*)(WuT + 131072);           // 147456
  float* wb    = (float*)(idxb + (size_t)B_*T_*P_); // 147456

  prep_kernel<<<1536, 256, 0, stream>>>(Wq, Wk, Wv, WT, Wu, WuT, sp, mvl, idxb, wb);
  qkv_mfma_kernel<<<dim3(16, 64), 256, 0, stream>>>(x, WT, Qh, Kh, Vh);
  attn_kernel<<<dim3(B_*T_, 2), 256, 0, stream>>>(Qh, Kh, Vh, idxb, wb, attnh);
  out_fused_mfma<<<dim3(256, 2), 256, 0, stream>>>(attnh, WuT, bu, out);
}

// Round 22
// 76.233 us; speedup vs baseline: 1.0212x; 1.0212x over previous
//
#include <hip/hip_runtime.h>
#include <math.h>

#define B_    2
#define T_    2048
#define EMB_  128
#define NH_   8
#define M_    9
#define P_    36
#define GADD_ 2

typedef _Float16 f16;
typedef __attribute__((ext_vector_type(2))) _Float16 f16x2;
typedef __attribute__((ext_vector_type(4))) _Float16 f16x4;
typedef __attribute__((ext_vector_type(8))) _Float16 f16x8;
typedef __attribute__((ext_vector_type(4))) float f32x4;

// ---------------- Threefry-2x32 (jax PRNG) ----------------
__device__ __forceinline__ unsigned rotl32(unsigned x, int r){ return (x<<r)|(x>>(32-r)); }

struct U2 { unsigned x, y; };

__device__ __forceinline__ U2 tf2x32(U2 key, U2 ctr){
  unsigned ks[3] = { key.x, key.y, key.x ^ key.y ^ 0x1BD11BDAu };
  unsigned x0 = ctr.x + ks[0], x1 = ctr.y + ks[1];
  const int rotA[4] = {13,15,26,6}, rotB[4] = {17,29,16,24};
  #pragma unroll
  for (int r = 0; r < 5; ++r){
    const int* rr = (r & 1) ? rotB : rotA;
    #pragma unroll
    for (int i = 0; i < 4; ++i){ x0 += x1; x1 = rotl32(x1, rr[i]); x1 ^= x0; }
    x0 += ks[(r+1)%3];
    x1 += ks[(r+2)%3] + (unsigned)(r+1);
  }
  return { x0, x1 };
}

// randint(key(42),(B,T,M,GADD),0,T), partitionable threefry path.
__device__ unsigned glob_rand(unsigned f){
  U2 k2 = tf2x32({0u, 42u}, {0u, 1u});
  U2 o  = tf2x32(k2, {0u, f});
  return (o.x ^ o.y) & (unsigned)(T_-1);
}

__device__ __forceinline__ f16x2 as_f16x2(unsigned u){ return __builtin_bit_cast(f16x2, u); }
__device__ __forceinline__ unsigned as_u32(f16x2 v){ return __builtin_bit_cast(unsigned, v); }

// ---------------- kernel 0: fused prep ----------------
__device__ __forceinline__ void tconv_body(const float* __restrict__ A,
    f16* __restrict__ o, int R, int C, int r0, int c0, float scale,
    float (*tile)[33]){
  const int tx = threadIdx.x & 31, ty = threadIdx.x >> 5;
  #pragma unroll
  for (int i = 0; i < 32; i += 8)
    tile[ty+i][tx] = A[(size_t)(r0+ty+i)*C + c0+tx];
  __syncthreads();
  #pragma unroll
  for (int i = 0; i < 32; i += 8)
    o[(size_t)(c0+ty+i)*R + (r0+tx)] = (f16)(tile[tx][ty+i] * scale);
}

__global__ __launch_bounds__(256) void prep_kernel(
    const float* __restrict__ x, f16* __restrict__ xh,
    const float* __restrict__ Wq, const float* __restrict__ Wk, const float* __restrict__ Wv,
    f16* __restrict__ WT,
    const float* __restrict__ Wu, f16* __restrict__ WuT,
    const float* __restrict__ sp, const float* __restrict__ mvals,
    int* __restrict__ idx_out, float* __restrict__ w_out){
  __shared__ float tile[32][33];
  __shared__ int   s_idx[4][P_];
  __shared__ float s_dens[4][P_][M_];
  __shared__ float s_col[4][M_];
  const int bid = blockIdx.x;
  const float sc = 0.29730177875068026f; // 128^-0.25

  if (bid < 512){
    const int i = (bid*256 + threadIdx.x)*4;
    float4 v = *(const float4*)(x + i);
    f16x4 p = { (f16)v.x, (f16)v.y, (f16)v.z, (f16)v.w };
    *(f16x4*)(xh + i) = p;
    return;
  }
  if (bid < 896){
    const int zz = bid - 512;
    const int z = zz >> 7, rem = zz & 127;
    const int by = rem >> 5, bx = rem & 31;       // [128][1024]: 4 x 32 tiles
    const float* A = (z==0) ? Wq : (z==1) ? Wk : Wv;
    tconv_body(A, WT + (size_t)z*1024*128, 128, 1024, by*32, bx*32, (z<2)?sc:1.0f, tile);
    return;
  }
  if (bid < 1024){
    const int idx2 = bid - 896;
    const int by = idx2 >> 2, bx = idx2 & 3;      // [1024][128]: 32 x 4 tiles
    tconv_body(Wu, WuT, 1024, 128, by*32, bx*32, 1.0f, tile);
    return;
  }

  // ---- idx + weights: 4 bt per block (one per wave) ----
  const int g  = threadIdx.x >> 6;
  const int p  = threadIdx.x & 63;
  const int bt = (bid - 1024)*4 + g;
  const int t  = bt & (T_-1);

  const float dil  = sp[0];
  const float xs   = sp[1] + 2.0f;
  const float sigma = xs + log1pf(expf(-xs)) + 1e-7f;

  if (p < P_){
    const int m = p >> 2, j = p & 3;
    const float mean = fminf(fmaxf((float)t + (float)(m-4)*dil, 0.f), (float)(T_-1));
    int id;
    if      (j == 0) id = (int)floorf(mean);
    else if (j == 1) id = min((int)floorf(mean) + 1, T_-1);
    else {
      const unsigned f = ((unsigned)bt * M_ + (unsigned)m) * GADD_ + (unsigned)(j-2);
      id = (int)glob_rand(f);
    }
    s_idx[g][p] = id;
  }
  __syncthreads();
  if (p < P_){
    const int myid = s_idx[g][p];
    bool dup = false;
    for (int q = 0; q < p; ++q) dup |= (s_idx[g][q] == myid);
    const float pf = (float)myid;
    #pragma unroll
    for (int m = 0; m < M_; ++m){
      const float mean = fminf(fmaxf((float)t + (float)(m-4)*dil, 0.f), (float)(T_-1));
      const float d = (pf - mean) / sigma;
      s_dens[g][p][m] = dup ? 0.f : expf(-0.5f * d * d);
    }
  }
  __syncthreads();
  if (p < M_){
    float s = 0.f;
    for (int q = 0; q < P_; ++q) s += s_dens[g][q][p];
    s_col[g][p] = s;
  }
  __syncthreads();
  if (p < P_){
    float w = 0.f;
    #pragma unroll
    for (int m = 0; m < M_; ++m) w += s_dens[g][p][m] / s_col[g][m] * mvals[m];
    idx_out[bt*P_ + p] = s_idx[g][p];
    w_out[bt*P_ + p]   = w;
  }
}

// ---------------- kernel 2: QKV via f16 MFMA, z-merged, coalesced stores (barrier-free) ----------------
// grid (16, 64), 256 thr = 4 waves; wave: 16M x 64N, K=128, 3 outputs.
__global__ __launch_bounds__(256) void qkv_mfma_kernel(const f16* __restrict__ xh,
    const f16* __restrict__ WT,
    f16* __restrict__ Qh, f16* __restrict__ Kh, f16* __restrict__ Vh){
  const int w  = threadIdx.x >> 6, l = threadIdx.x & 63;
  const int m0 = blockIdx.y*64 + w*16;
  const int n0 = blockIdx.x*64;
  const int lr = l & 15, lk = l >> 4;

  __shared__ f16 s_t[4][16][72];   // per-wave transpose tile, 9.2 KB

  f16x8 a[4];
  #pragma unroll
  for (int kc = 0; kc < 4; ++kc)
    a[kc] = *(const f16x8*)(xh + (size_t)(m0+lr)*128 + kc*32 + lk*8);

  for (int z = 0; z < 3; ++z){
    const f16* __restrict__ WTz = WT + (size_t)z * 1024 * 128;
    f16* __restrict__ Outh = (z==0) ? Qh : (z==1) ? Kh : Vh;
    f32x4 acc[4] = {};
    #pragma unroll
    for (int nf = 0; nf < 4; ++nf){
      #pragma unroll
      for (int kc = 0; kc < 4; ++kc){
        f16x8 b = *(const f16x8*)(WTz + (size_t)(n0+nf*16+lr)*128 + kc*32 + lk*8);
        acc[nf] = __builtin_amdgcn_mfma_f32_16x16x32_f16(a[kc], b, acc[nf], 0, 0, 0);
      }
    }
    // fragment -> wave-local LDS tile (no barrier: single-wave producer/consumer)
    #pragma unroll
    for (int nf = 0; nf < 4; ++nf){
      #pragma unroll
      for (int r = 0; r < 4; ++r)
        s_t[w][lk*4 + r][nf*16 + lr] = (f16)acc[nf][r];
    }
    // coalesced store: 2 x (8 rows x 128B lines)
    #pragma unroll
    for (int half = 0; half < 2; ++half){
      const int row = (l >> 3) + half*8;
      const int seg = l & 7;
      f16x8 v = *(const f16x8*)(&s_t[w][row][seg*8]);
      *(f16x8*)(Outh + (size_t)(m0+row)*1024 + n0 + seg*8) = v;
    }
  }
}

// ---------------- kernel 3: gather-attention (uint4 gathers, 4 pts/instr) ----------------
// grid (4096, 2), 256 thr = 4 waves = 4 heads (h = by*4 + w).
// Lane: pg=lane>>4 owns points 4c+pg (c=0..8); li=lane&15 owns dims li*8..+8.
#define RSTR 37
#define NHB  4
__global__ __launch_bounds__(256) void attn_kernel(const f16* __restrict__ Qh,
    const f16* __restrict__ K, const f16* __restrict__ V,
    const int* __restrict__ idx, const float* __restrict__ wts,
    f16* __restrict__ outh){
  const int bid = blockIdx.x;
  const int bt  = ((bid & 7) << 9) | (bid >> 3);   // XCD swizzle, bijective
  const int b   = bt >> 11;
  const int hw   = threadIdx.x >> 6, lane = threadIdx.x & 63;
  const int h    = blockIdx.y*NHB + hw;
  const int pg = lane >> 4, li = lane & 15;

  __shared__ int   s_koff[P_];
  __shared__ float s_w[P_];
  __shared__ float s_red[NHB][16*RSTR];
  __shared__ float s_a[NHB][36];

  if (threadIdx.x < P_){
    s_koff[threadIdx.x] = idx[bt*P_ + threadIdx.x] << 10;   // element offset ip*1024
    s_w[threadIdx.x]    = wts[bt*P_ + threadIdx.x];
  }
  __syncthreads();

  const size_t rowBase = (size_t)bt*1024 + h*EMB_;
  const uint4 qu = *(const uint4*)(Qh + rowBase + li*8);
  const f16x2 q01 = as_f16x2(qu.x), q23 = as_f16x2(qu.y);
  const f16x2 q45 = as_f16x2(qu.z), q67 = as_f16x2(qu.w);
  const f16* __restrict__ Kb = K + (size_t)b*T_*1024 + h*EMB_ + li*8;
  const f16* __restrict__ Vb = V + (size_t)b*T_*1024 + h*EMB_ + li*8;

  int ko[9];
  #pragma unroll
  for (int c = 0; c < 9; ++c) ko[c] = s_koff[4*c + pg];

  // ---- Phase A: 9 uint4 K loads; 8-dim partial dots ----
  uint4 kU[9];
  #pragma unroll
  for (int c = 0; c < 9; ++c) kU[c] = *(const uint4*)(Kb + ko[c]);

  float pr[9];
  #pragma unroll
  for (int c = 0; c < 9; ++c){
    pr[c] = __builtin_amdgcn_fdot2(as_f16x2(kU[c].x), q01,
            __builtin_amdgcn_fdot2(as_f16x2(kU[c].y), q23,
            __builtin_amdgcn_fdot2(as_f16x2(kU[c].z), q45,
            __builtin_amdgcn_fdot2(as_f16x2(kU[c].w), q67, 0.f, false),
            false), false), false);
  }

  // ---- Phase B: LDS transpose (wave-local), column sum over 16 li-rows ----
  float* __restrict__ red = s_red[hw];
  {
    float* __restrict__ dst = red + li*RSTR + pg;
    #pragma unroll
    for (int c = 0; c < 9; ++c) dst[4*c] = pr[c];
  }
  const int pcol = (lane < P_) ? lane : 0;
  float s0=0.f, s1=0.f, s2=0.f, s3=0.f;
  #pragma unroll
  for (int r = 0; r < 16; r += 4){
    s0 += red[(r+0)*RSTR + pcol];
    s1 += red[(r+1)*RSTR + pcol];
    s2 += red[(r+2)*RSTR + pcol];
    s3 += red[(r+3)*RSTR + pcol];
  }
  const float logit = (s0+s1)+(s2+s3);

  // ---- softmax (lane-per-point) ----
  float val = (lane < P_) ? logit * s_w[pcol] : -INFINITY;
  float mx = val;
  #pragma unroll
  for (int off = 32; off; off >>= 1) mx = fmaxf(mx, __shfl_xor(mx, off));
  float e = (lane < P_) ? expf(val - mx) : 0.f;
  float s = e;
  #pragma unroll
  for (int off = 32; off; off >>= 1) s += __shfl_xor(s, off);
  if (lane < P_) s_a[hw][lane] = e / s;

  // ---- Phase C: 9 uint4 V loads, packed f16 fma over own pg's points ----
  f16x2 a01 = {(f16)0.f,(f16)0.f}, a23 = a01, a45 = a01, a67 = a01;
  #pragma unroll
  for (int c = 0; c < 9; ++c){
    const f16 awh = (f16)s_a[hw][4*c + pg];
    const f16x2 vw = { awh, awh };
    const uint4 u = *(const uint4*)(Vb + ko[c]);
    a01 = vw * as_f16x2(u.x) + a01;
    a23 = vw * as_f16x2(u.y) + a23;
    a45 = vw * as_f16x2(u.z) + a45;
    a67 = vw * as_f16x2(u.w) + a67;
  }
  // fold over the 4 pg groups
  a01 = a01 + as_f16x2(__shfl_xor((int)as_u32(a01), 16));
  a23 = a23 + as_f16x2(__shfl_xor((int)as_u32(a23), 16));
  a45 = a45 + as_f16x2(__shfl_xor((int)as_u32(a45), 16));
  a67 = a67 + as_f16x2(__shfl_xor((int)as_u32(a67), 16));
  a01 = a01 + as_f16x2(__shfl_xor((int)as_u32(a01), 32));
  a23 = a23 + as_f16x2(__shfl_xor((int)as_u32(a23), 32));
  a45 = a45 + as_f16x2(__shfl_xor((int)as_u32(a45), 32));
  a67 = a67 + as_f16x2(__shfl_xor((int)as_u32(a67), 32));
  if (pg == 0){
    uint4 pck = { as_u32(a01), as_u32(a23), as_u32(a45), as_u32(a67) };
    *(uint4*)(outh + rowBase + li*8) = pck;
  }
}

// ---------------- kernel 4: fused output GEMM (in-block split-K) + bias ----------------
// grid (256 m-tiles, 2 n-halves), 256 thr = 4 waves. Block: 16 rows x 64 cols.
// Wave w covers K-chunk [w*256, w*256+256): 4 nf x 8 kc MFMAs -> LDS -> reduce+bias.
__global__ __launch_bounds__(256) void out_fused_mfma(const f16* __restrict__ Ah,
    const f16* __restrict__ WuT, const float* __restrict__ bu,
    float* __restrict__ out){
  const int w  = threadIdx.x >> 6, l = threadIdx.x & 63;
  const int m0 = blockIdx.x*16;
  const int n0 = blockIdx.y*64;
  const int k0 = w*256;
  const int lr = l & 15, lk = l >> 4;

  __shared__ float s_part[4][16][64];   // 16 KB

  const f16* __restrict__ arow = Ah + (size_t)(m0+lr)*1024 + k0 + lk*8;
  f32x4 acc[4] = {};
  #pragma unroll
  for (int kc = 0; kc < 8; ++kc){
    f16x8 a = *(const f16x8*)(arow + kc*32);
    #pragma unroll
    for (int nf = 0; nf < 4; ++nf){
      f16x8 b = *(const f16x8*)(WuT + (size_t)(n0+nf*16+lr)*1024 + k0 + kc*32 + lk*8);
      acc[nf] = __builtin_amdgcn_mfma_f32_16x16x32_f16(a, b, acc[nf], 0, 0, 0);
    }
  }
  #pragma unroll
  for (int nf = 0; nf < 4; ++nf){
    #pragma unroll
    for (int r = 0; r < 4; ++r)
      s_part[w][lk*4 + r][nf*16 + lr] = acc[nf][r];
  }
  __syncthreads();

  // reduce: 1024 outputs = 256 thr x float4
  const int r  = threadIdx.x >> 4;          // 0..15
  const int c0 = (threadIdx.x & 15) * 4;    // 0..60
  float4 a0 = *(const float4*)(&s_part[0][r][c0]);
  float4 a1 = *(const float4*)(&s_part[1][r][c0]);
  float4 a2 = *(const float4*)(&s_part[2][r][c0]);
  float4 a3 = *(const float4*)(&s_part[3][r][c0]);
  float4 bias = *(const float4*)(bu + n0 + c0);
  float4 v = { (a0.x+a1.x)+(a2.x+a3.x)+bias.x,
               (a0.y+a1.y)+(a2.y+a3.y)+bias.y,
               (a0.z+a1.z)+(a2.z+a3.z)+bias.z,
               (a0.w+a1.w)+(a2.w+a3.w)+bias.w };
  *(float4*)(out + (size_t)(m0+r)*128 + n0 + c0) = v;
}

// ---------------- launch ----------------
extern "C" void kernel_launch(void* const* d_in, const int* in_sizes, int n_in,
                              void* d_out, int out_size, void* d_ws, size_t ws_size,
                              hipStream_t stream){
  (void)in_sizes; (void)n_in; (void)out_size; (void)ws_size;
  const float* x    = (const float*)d_in[0];
  const float* sp   = (const float*)d_in[1];
  const float* mvl  = (const float*)d_in[2];
  const float* Wq   = (const float*)d_in[3];
  const float* Wk   = (const float*)d_in[4];
  const float* Wv   = (const float*)d_in[5];
  const float* Wu   = (const float*)d_in[6];
  const float* bu   = (const float*)d_in[7];
  float* out = (float*)d_out;

  const size_t n = (size_t)B_*NH_*T_*EMB_;       // 4,194,304
  f16*   Qh    = (f16*)d_ws;                     // n
  f16*   Kh    = Qh + n;                         // n
  f16*   Vh    = Kh + n;                         // n
  f16*   attnh = Vh + n;                         // n
  f16*   xh    = attnh + n;                      // 524288
  f16*   WT    = xh + (size_t)B_*T_*EMB_;        // 3*131072
  f16*   WuT   = WT + 3*131072;                  // 131072
  int*   idxb  = (int*)(WuT + 131072);           // 147456
  float* wb    = (float*)(idxb + (size_t)B_*T_*P_); // 147456

  prep_kernel<<<2048, 256, 0, stream>>>(x, xh, Wq, Wk, Wv, WT, Wu, WuT, sp, mvl, idxb, wb);
  qkv_mfma_kernel<<<dim3(16, 64), 256, 0, stream>>>(xh, WT, Qh, Kh, Vh);
  attn_kernel<<<dim3(B_*T_, 2), 256, 0, stream>>>(Qh, Kh, Vh, idxb, wb, attnh);
  out_fused_mfma<<<dim3(256, 2), 256, 0, stream>>>(attnh, WuT, bu, out);
}